// Round 11
// baseline (161.167 us; speedup 1.0000x reference)
//
#include <hip/hip_runtime.h>
#include <math.h>

#define NSITE 2048

// flat output offsets (floats), reference return order
#define OFF_XOUT 0
#define OFF_AGR  (NSITE*64)                // 131072
#define OFF_POSE (OFF_AGR + NSITE*64)      // 262144
#define OFF_XP   (OFF_POSE + NSITE*128)    // 524288

// guarded normalize matching ref semantics: out_c = (mu_c==0) ? 0 : mu_c/||mu||
__device__ __forceinline__ void norm2_guard(float x, float y, float* ox, float* oy) {
    const float n2  = x*x + y*y;
    const float inv = (n2 > 0.f) ? rsqrtf(n2) : 0.f;
    *ox = x*inv; *oy = y*inv;
}

// ---------------------------------------------------------------------------
// Fused kernel (v2 — identical logic to R8-R10 submission, symbol renamed).
// Grid: (g = co-group 0..7, sb = site-block 0..255), 256 thr.
// Phase 1: each wave runs the R7-validated capsA pipeline for 2 sites,
//   producing h (8 sites x 128) + meta in LDS. Bit-identical to R7's capsA
//   (all ops wave-internal; same shuffle/fma order). g==0 blocks also write
//   x_out and xp (identical across g -> computed once).
// Phase 2: R7-validated capsB routing VERBATIM, h/meta read from LDS.
//   The routing fixed point is bistable at >=1 (site,co) with a ~1e-7 theta
//   margin (R4/R6: MFMA-split thetas of very different accuracy both land on
//   a wrong attractor at identical absmax 0.164). DO NOT change any
//   arithmetic or reduction order in either phase.
// ---------------------------------------------------------------------------
__global__ __launch_bounds__(256) void caps_fused2(
    const float* __restrict__ x, const float* __restrict__ a,
    const float* __restrict__ pose,
    const float* __restrict__ tg1, const float* __restrict__ lin_w,
    const float* __restrict__ lin_b, const float* __restrict__ tg2,
    const float* __restrict__ alpha, const float* __restrict__ beta,
    float* __restrict__ out)
{
    const int g    = blockIdx.x;            // co-group 0..7
    const int sb   = blockIdx.y;            // site block 0..255 (8 sites)
    const int tid  = threadIdx.x;
    const int wave = tid >> 6, lane = tid & 63;

    __shared__ float hs[8*128];       // h for the block's 8 sites (4 KB)
    __shared__ float meta_s[8*2];     // (Sa, cnt) per local site
    __shared__ float stp[4][4][64];   // per-wave tpos scratch (4 KB)
    __shared__ float xps[4][32];      // per-wave pooled x-max scratch

    // ---------------- Phase 1: h + meta (2 sites per wave) ----------------
    {
        const int ci = lane & 31, p0 = lane >> 5;       // p0 in {0,1}
        #pragma unroll
        for (int si = 0; si < 2; ++si) {
            const int sl = wave*2 + si;                 // local site 0..7
            const int s  = sb*8 + sl;
            const int b  = s >> 8, hp = (s >> 4) & 15, wp = s & 15;

            const int base = ((b*32 + 2*hp)*32 + 2*wp)*32 + ci;
            const int i0 = base + p0*32;            // p = p0   (dh=0, dw=p0)
            const int i1 = base + 1024 + p0*32;     // p = p0+2 (dh=1, dw=p0)
            const float2 pe0 = ((const float2*)pose)[i0];
            const float2 pe1 = ((const float2*)pose)[i1];
            const float  x0  = x[i0], x1 = x[i1];
            const float  a0  = a[i0], a1 = a[i1];

            // pose pooling sum in exact reference order ((p0+p1)+p2)+p3
            const float o0x = __shfl_xor(pe0.x, 32, 64);
            const float o0y = __shfl_xor(pe0.y, 32, 64);
            const float o1x = __shfl_xor(pe1.x, 32, 64);
            const float o1y = __shfl_xor(pe1.y, 32, 64);
            const bool first = (p0 == 0);
            const float A0x = first ? pe0.x : o0x,  A1x = first ? o0x : pe0.x;
            const float A2x = first ? pe1.x : o1x,  A3x = first ? o1x : pe1.x;
            const float A0y = first ? pe0.y : o0y,  A1y = first ? o0y : pe0.y;
            const float A2y = first ? pe1.y : o1y,  A3y = first ? o1y : pe1.y;
            float mx = ((A0x + A1x) + A2x) + A3x;
            float my = ((A0y + A1y) + A2y) + A3y;

            // x max-pool, Sa, count(a != 0)
            float xm = fmaxf(x0, x1);
            xm = fmaxf(xm, __shfl_xor(xm, 32, 64));
            float sa  = a0 + a1;
            float cnt = (a0 != 0.f ? 1.f : 0.f) + (a1 != 0.f ? 1.f : 0.f);
            sa  += __shfl_xor(sa,  32, 64);
            cnt += __shfl_xor(cnt, 32, 64);
            #pragma unroll
            for (int m = 1; m <= 16; m <<= 1) {
                sa  += __shfl_xor(sa,  m, 64);
                cnt += __shfl_xor(cnt, m, 64);
            }
            if (lane == 0) { meta_s[sl*2] = sa; meta_s[sl*2 + 1] = cnt; }
            if (p0 == 0) {
                xps[wave][ci] = xm;
                if (g == 0) out[OFF_XP + s*32 + ci] = xm;
            }

            // guarded mean
            {
                const float n   = sqrtf(mx*mx + my*my);
                const float den = n + (n == 0.f ? 1.f : 0.f);
                mx /= den; my /= den;
            }

            // tpos = [[mx,my],[-my,mx]] @ (hh,ww); hh = dh-0.5, ww = p0-0.5
            {
                const float ww_ = (float)p0 - 0.5f;
                const float t0x = -0.5f*mx + my*ww_;    // p0   (hh=-0.5)
                const float t0y =  0.5f*my + mx*ww_;
                const float t1x =  0.5f*mx + my*ww_;    // p0+2 (hh=+0.5)
                const float t1y = -0.5f*my + mx*ww_;
                ((float2*)stp[wave][p0    ])[ci] = make_float2(t0x, t0y);
                ((float2*)stp[wave][p0 + 2])[ci] = make_float2(t1x, t1y);
            }
            __syncthreads();

            // h[p][j] = sum_m tg1[j][m]*tpos[p][m]; lane: (p0,j=ci),(p0+2,j=ci)
            {
                const float4* w4 = (const float4*)(tg1 + ci*64);
                const float4* r0 = (const float4*)stp[wave][p0];
                const float4* r1 = (const float4*)stp[wave][p0 + 2];
                float h0 = 0.f, h1 = 0.f;
                #pragma unroll
                for (int k = 0; k < 16; ++k) {
                    const float4 wv = w4[k], u = r0[k], v = r1[k];
                    h0 += wv.x*u.x + wv.y*u.y + wv.z*u.z + wv.w*u.w;
                    h1 += wv.x*v.x + wv.y*v.y + wv.z*v.z + wv.w*v.w;
                }
                hs[sl*128 + p0*32 + ci]       = h0;
                hs[sl*128 + (p0 + 2)*32 + ci] = h1;
            }

            // x_out[co=lane] = lin_b + sum_ci xp[ci]*lin_w[co][ci]  (g==0 only)
            if (g == 0) {
                float acc = lin_b[lane];
                const float4* lw = (const float4*)(lin_w + lane*32);
                const float4* xv = (const float4*)xps[wave];
                #pragma unroll
                for (int k = 0; k < 8; ++k) {
                    const float4 wv = lw[k], u = xv[k];
                    acc += wv.x*u.x + wv.y*u.y + wv.z*u.z + wv.w*u.w;
                }
                out[OFF_XOUT + s*64 + lane] = acc;
            }
            __syncthreads();
        }
    }

    // ---------------- Phase 2: routing (R7 capsB verbatim) ----------------
    const int co   = g*8 + wave*2 + (lane >> 5);
    const int ci   = lane & 31;

    // cache tg2 row (32 floats) in registers -- reused for 8 sites
    float4 r[8];
    {
        const float4* rp = (const float4*)(tg2 + (co*32 + ci)*32);
        #pragma unroll
        for (int k = 0; k < 8; ++k) r[k] = rp[k];
    }
    const float alp = alpha[0];
    const float bet = beta[0] - 1.0f;

    for (int sl = 0; sl < 8; ++sl) {
        const int s = sb*8 + sl;
        // theta[p] = tg2_row(co*32+ci) . h[s][p]   (LDS broadcast reads)
        const float4* h4 = (const float4*)(hs + sl*128);
        float th0 = 0.f, th1 = 0.f, th2 = 0.f, th3 = 0.f;
        #pragma unroll
        for (int k = 0; k < 8; ++k) {
            const float4 rk = r[k];
            const float4 ha = h4[k];
            const float4 hb = h4[8  + k];
            const float4 hc = h4[16 + k];
            const float4 hd = h4[24 + k];
            th0 += rk.x*ha.x + rk.y*ha.y + rk.z*ha.z + rk.w*ha.w;
            th1 += rk.x*hb.x + rk.y*hb.y + rk.z*hb.z + rk.w*hb.w;
            th2 += rk.x*hc.x + rk.y*hc.y + rk.z*hc.z + rk.w*hc.w;
            th3 += rk.x*hd.x + rk.y*hd.y + rk.z*hd.z + rk.w*hd.w;
        }
        const float th[4] = {th0, th1, th2, th3};

        const int b   = s >> 8, hpi = (s >> 4) & 15, wpi = s & 15;
        const int base = ((b*32 + 2*hpi)*32 + 2*wpi)*32 + ci;

        float Sx = 0.f, Sy = 0.f, Sxx = 0.f, Sxy = 0.f, Syy = 0.f;
        #pragma unroll
        for (int p = 0; p < 4; ++p) {
            const int idx = base + (p >> 1)*1024 + (p & 1)*32;
            const float2 pe = ((const float2*)pose)[idx];
            const float  av = a[idx];
            float sn, cs;
            __sincosf(th[p], &sn, &cs);
            const float vx = pe.x*cs - pe.y*sn;   // vote = rot(theta) @ pose
            const float vy = pe.y*cs + pe.x*sn;
            const float ax = av*vx, ay = av*vy;
            Sx += ax; Sy += ay;
            Sxx += ax*vx; Sxy += ax*vy; Syy += ay*vy;
        }
        // one butterfly over the 32 lanes of this co-half (masks 1..16)
        #pragma unroll
        for (int m = 1; m <= 16; m <<= 1) {
            Sx  += __shfl_xor(Sx,  m, 64);
            Sy  += __shfl_xor(Sy,  m, 64);
            Sxx += __shfl_xor(Sxx, m, 64);
            Sxy += __shfl_xor(Sxy, m, 64);
            Syy += __shfl_xor(Syy, m, 64);
        }

        // fixed point on moments (all lanes redundantly; stores from lane 0/32)
        float px, py;
        norm2_guard(Sx, Sy, &px, &py);            // p0 (weight = a)
        float qx = px, qy = py;
        #pragma unroll
        for (int it = 0; it < 3; ++it) {
            qx = px; qy = py;                     // ends as p2
            const float mx = Sx + px*Sxx + py*Sxy;
            const float my = Sy + px*Sxy + py*Syy;
            norm2_guard(mx, my, &px, &py);        // ends as p3
        }
        const float sa_s  = meta_s[sl*2];
        const float cnt_s = meta_s[sl*2 + 1];
        const float nd_sum = 0.25f*(sa_s + (px + qx)*Sx + (py + qy)*Sy
                           + px*qx*Sxx + (px*qy + py*qx)*Sxy + py*qy*Syy);
        const float wsum = cnt_s;
        const float msk  = (wsum != 0.f) ? 1.f : 0.f;
        const float nd   = nd_sum / (wsum + (1.f - msk)) * msk;
        const float z    = alp*nd + bet;
        const float agr  = msk / (1.f + __expf(-z));

        if ((lane & 31) == 0) {
            out[OFF_AGR  + s*64  + co]       = agr;
            out[OFF_POSE + s*128 + co*2]     = px;
            out[OFF_POSE + s*128 + co*2 + 1] = py;
        }
    }
}

extern "C" void kernel_launch(void* const* d_in, const int* in_sizes, int n_in,
                              void* d_out, int out_size, void* d_ws, size_t ws_size,
                              hipStream_t stream) {
    const float* x     = (const float*)d_in[0];
    const float* a     = (const float*)d_in[1];
    const float* pose  = (const float*)d_in[2];
    const float* alpha = (const float*)d_in[3];
    const float* beta  = (const float*)d_in[4];
    const float* lin_w = (const float*)d_in[5];
    const float* lin_b = (const float*)d_in[6];
    const float* tg1   = (const float*)d_in[7];
    const float* tg2   = (const float*)d_in[8];
    float* out = (float*)d_out;
    (void)d_ws; (void)ws_size;

    caps_fused2<<<dim3(8, NSITE/8), 256, 0, stream>>>(
        x, a, pose, tg1, lin_w, lin_b, tg2, alpha, beta, out);
}

// Round 12
// 135.503 us; speedup vs baseline: 1.1894x; 1.1894x over previous
//
#include <hip/hip_runtime.h>
#include <math.h>

#define NSITE 2048

// flat output offsets (floats), reference return order
#define OFF_XOUT 0
#define OFF_AGR  (NSITE*64)                // 131072
#define OFF_POSE (OFF_AGR + NSITE*64)      // 262144
#define OFF_XP   (OFF_POSE + NSITE*128)    // 524288

// ws layout: ws_h [2048][128] floats (1 MB), then ws_meta [2048] float2 (16 KB)
#define WS_META_OFF (NSITE*128)

// guarded normalize matching ref semantics: out_c = (mu_c==0) ? 0 : mu_c/||mu||
__device__ __forceinline__ void norm2_guard(float x, float y, float* ox, float* oy) {
    const float n2  = x*x + y*y;
    const float inv = (n2 > 0.f) ? rsqrtf(n2) : 0.f;
    *ox = x*inv; *oy = y*inv;
}

// ---------------------------------------------------------------------------
// Kernel A: one wave per site; 4 sites per 256-thread block; 512 blocks.
// R7-validated VERBATIM. ~5 us.
// ---------------------------------------------------------------------------
__global__ __launch_bounds__(256) void capsA(
    const float* __restrict__ x, const float* __restrict__ a,
    const float* __restrict__ pose,
    const float* __restrict__ tg1, const float* __restrict__ lin_w,
    const float* __restrict__ lin_b, float* __restrict__ out,
    float* __restrict__ ws)
{
    const int wave = threadIdx.x >> 6, lane = threadIdx.x & 63;
    const int s  = blockIdx.x*4 + wave;
    const int b  = s >> 8, hp = (s >> 4) & 15, wp = s & 15;
    const int ci = lane & 31, p0 = lane >> 5;           // p0 in {0,1}

    __shared__ float stp[4][4][64];   // tpos per site: [wave][p][2ci+c]
    __shared__ float xps[4][32];      // pooled x-max per site

    const int base = ((b*32 + 2*hp)*32 + 2*wp)*32 + ci;
    const int i0 = base + p0*32;            // p = p0   (dh=0, dw=p0)
    const int i1 = base + 1024 + p0*32;     // p = p0+2 (dh=1, dw=p0)
    const float2 pe0 = ((const float2*)pose)[i0];
    const float2 pe1 = ((const float2*)pose)[i1];
    const float  x0  = x[i0], x1 = x[i1];
    const float  a0  = a[i0], a1 = a[i1];

    // pose pooling sum in exact reference order ((p0+p1)+p2)+p3
    const float o0x = __shfl_xor(pe0.x, 32, 64);
    const float o0y = __shfl_xor(pe0.y, 32, 64);
    const float o1x = __shfl_xor(pe1.x, 32, 64);
    const float o1y = __shfl_xor(pe1.y, 32, 64);
    const bool first = (p0 == 0);
    const float A0x = first ? pe0.x : o0x,  A1x = first ? o0x : pe0.x;
    const float A2x = first ? pe1.x : o1x,  A3x = first ? o1x : pe1.x;
    const float A0y = first ? pe0.y : o0y,  A1y = first ? o0y : pe0.y;
    const float A2y = first ? pe1.y : o1y,  A3y = first ? o1y : pe1.y;
    float mx = ((A0x + A1x) + A2x) + A3x;
    float my = ((A0y + A1y) + A2y) + A3y;

    // x max-pool, Sa, count(a != 0)
    float xm = fmaxf(x0, x1);
    xm = fmaxf(xm, __shfl_xor(xm, 32, 64));
    float sa  = a0 + a1;
    float cnt = (a0 != 0.f ? 1.f : 0.f) + (a1 != 0.f ? 1.f : 0.f);
    sa  += __shfl_xor(sa,  32, 64);
    cnt += __shfl_xor(cnt, 32, 64);
    // site totals over ci
    #pragma unroll
    for (int m = 1; m <= 16; m <<= 1) {
        sa  += __shfl_xor(sa,  m, 64);
        cnt += __shfl_xor(cnt, m, 64);
    }
    if (lane == 0) ((float2*)(ws + WS_META_OFF))[s] = make_float2(sa, cnt);
    if (p0 == 0) {
        out[OFF_XP + s*32 + ci] = xm;
        xps[wave][ci] = xm;
    }

    // guarded mean
    {
        const float n   = sqrtf(mx*mx + my*my);
        const float den = n + (n == 0.f ? 1.f : 0.f);
        mx /= den; my /= den;
    }

    // tpos = [[mx,my],[-my,mx]] @ (hh,ww); hh = dh-0.5, ww = p0-0.5
    {
        const float ww_ = (float)p0 - 0.5f;
        const float t0x = -0.5f*mx + my*ww_;    // p0   (hh=-0.5)
        const float t0y =  0.5f*my + mx*ww_;
        const float t1x =  0.5f*mx + my*ww_;    // p0+2 (hh=+0.5)
        const float t1y = -0.5f*my + mx*ww_;
        ((float2*)stp[wave][p0    ])[ci] = make_float2(t0x, t0y);
        ((float2*)stp[wave][p0 + 2])[ci] = make_float2(t1x, t1y);
    }
    __syncthreads();

    // h[p][j] = sum_m tg1[j][m]*tpos[p][m]; lane does (p0, j=ci), (p0+2, j=ci)
    {
        const float4* w4 = (const float4*)(tg1 + ci*64);
        const float4* r0 = (const float4*)stp[wave][p0];
        const float4* r1 = (const float4*)stp[wave][p0 + 2];
        float h0 = 0.f, h1 = 0.f;
        #pragma unroll
        for (int k = 0; k < 16; ++k) {
            const float4 wv = w4[k], u = r0[k], v = r1[k];
            h0 += wv.x*u.x + wv.y*u.y + wv.z*u.z + wv.w*u.w;
            h1 += wv.x*v.x + wv.y*v.y + wv.z*v.z + wv.w*v.w;
        }
        ws[s*128 + p0*32 + ci]       = h0;
        ws[s*128 + (p0 + 2)*32 + ci] = h1;
    }

    // x_out[co=lane] = lin_b + sum_ci xp[ci]*lin_w[co][ci]
    {
        float acc = lin_b[lane];
        const float4* lw = (const float4*)(lin_w + lane*32);
        const float4* xv = (const float4*)xps[wave];
        #pragma unroll
        for (int k = 0; k < 8; ++k) {
            const float4 wv = lw[k], u = xv[k];
            acc += wv.x*u.x + wv.y*u.y + wv.z*u.z + wv.w*u.w;
        }
        out[OFF_XOUT + s*64 + lane] = acc;
    }
}

// ---------------------------------------------------------------------------
// Kernel B: moment-based routing, VALU fp32 theta. Same arithmetic as the
// R2/R7-validated kernel (absmax 0.0039) — DO NOT change any expression or
// reduction order (bistable fixed point at >=1 (site,co), ~1e-7 margin;
// R4/R6 evidence). Scheduling-only changes vs R7:
//   * grid dim3(8, 512): each wave owns 4 sites (was 8) -> 16384 waves,
//     4096 blocks = 16/CU for better balance / shorter tail.
//   * fully unrolled site loop -> cross-site ILP hides swizzle/sincos
//     latency chains.
// ---------------------------------------------------------------------------
__global__ __launch_bounds__(256) void capsB(
    const float* __restrict__ a, const float* __restrict__ pose,
    const float* __restrict__ tg2, const float* __restrict__ ws,
    const float* __restrict__ alpha, const float* __restrict__ beta,
    float* __restrict__ out)
{
    const int g    = blockIdx.x;            // co-group 0..7
    const int sb   = blockIdx.y;            // site block 0..511 (4 sites)
    const int tid  = threadIdx.x;
    const int wave = tid >> 6, lane = tid & 63;
    const int co   = g*8 + wave*2 + (lane >> 5);
    const int ci   = lane & 31;

    // cache tg2 row (32 floats) in registers -- reused for 4 sites
    float4 r[8];
    {
        const float4* rp = (const float4*)(tg2 + (co*32 + ci)*32);
        #pragma unroll
        for (int k = 0; k < 8; ++k) r[k] = rp[k];
    }
    const float alp = alpha[0];
    const float bet = beta[0] - 1.0f;
    const float2* ws_meta = (const float2*)(ws + WS_META_OFF);

    const int s0 = sb*4;
    #pragma unroll
    for (int sl = 0; sl < 4; ++sl) {
        const int s = s0 + sl;
        // theta[p] = tg2_row(co*32+ci) . h[s][p]   (h loads are wave-uniform)
        const float4* h4 = (const float4*)(ws + s*128);
        float th0 = 0.f, th1 = 0.f, th2 = 0.f, th3 = 0.f;
        #pragma unroll
        for (int k = 0; k < 8; ++k) {
            const float4 rk = r[k];
            const float4 ha = h4[k];
            const float4 hb = h4[8  + k];
            const float4 hc = h4[16 + k];
            const float4 hd = h4[24 + k];
            th0 += rk.x*ha.x + rk.y*ha.y + rk.z*ha.z + rk.w*ha.w;
            th1 += rk.x*hb.x + rk.y*hb.y + rk.z*hb.z + rk.w*hb.w;
            th2 += rk.x*hc.x + rk.y*hc.y + rk.z*hc.z + rk.w*hc.w;
            th3 += rk.x*hd.x + rk.y*hd.y + rk.z*hd.z + rk.w*hd.w;
        }
        const float th[4] = {th0, th1, th2, th3};

        const int b   = s >> 8, hpi = (s >> 4) & 15, wpi = s & 15;
        const int base = ((b*32 + 2*hpi)*32 + 2*wpi)*32 + ci;

        float Sx = 0.f, Sy = 0.f, Sxx = 0.f, Sxy = 0.f, Syy = 0.f;
        #pragma unroll
        for (int p = 0; p < 4; ++p) {
            const int idx = base + (p >> 1)*1024 + (p & 1)*32;
            const float2 pe = ((const float2*)pose)[idx];
            const float  av = a[idx];
            float sn, cs;
            __sincosf(th[p], &sn, &cs);
            const float vx = pe.x*cs - pe.y*sn;   // vote = rot(theta) @ pose
            const float vy = pe.y*cs + pe.x*sn;
            const float ax = av*vx, ay = av*vy;
            Sx += ax; Sy += ay;
            Sxx += ax*vx; Sxy += ax*vy; Syy += ay*vy;
        }
        // one butterfly over the 32 lanes of this co-half (masks 1..16)
        #pragma unroll
        for (int m = 1; m <= 16; m <<= 1) {
            Sx  += __shfl_xor(Sx,  m, 64);
            Sy  += __shfl_xor(Sy,  m, 64);
            Sxx += __shfl_xor(Sxx, m, 64);
            Sxy += __shfl_xor(Sxy, m, 64);
            Syy += __shfl_xor(Syy, m, 64);
        }

        // fixed point on moments (all lanes redundantly; stores from lane 0/32)
        float px, py;
        norm2_guard(Sx, Sy, &px, &py);            // p0 (weight = a)
        float qx = px, qy = py;
        #pragma unroll
        for (int it = 0; it < 3; ++it) {
            qx = px; qy = py;                     // ends as p2
            const float mx = Sx + px*Sxx + py*Sxy;
            const float my = Sy + px*Sxy + py*Syy;
            norm2_guard(mx, my, &px, &py);        // ends as p3
        }
        const float2 meta = ws_meta[s];           // (Sa, count(a!=0))
        const float nd_sum = 0.25f*(meta.x + (px + qx)*Sx + (py + qy)*Sy
                           + px*qx*Sxx + (px*qy + py*qx)*Sxy + py*qy*Syy);
        const float wsum = meta.y;
        const float msk  = (wsum != 0.f) ? 1.f : 0.f;
        const float nd   = nd_sum / (wsum + (1.f - msk)) * msk;
        const float z    = alp*nd + bet;
        const float agr  = msk / (1.f + __expf(-z));

        if ((lane & 31) == 0) {
            out[OFF_AGR  + s*64  + co]       = agr;
            out[OFF_POSE + s*128 + co*2]     = px;
            out[OFF_POSE + s*128 + co*2 + 1] = py;
        }
    }
}

extern "C" void kernel_launch(void* const* d_in, const int* in_sizes, int n_in,
                              void* d_out, int out_size, void* d_ws, size_t ws_size,
                              hipStream_t stream) {
    const float* x     = (const float*)d_in[0];
    const float* a     = (const float*)d_in[1];
    const float* pose  = (const float*)d_in[2];
    const float* alpha = (const float*)d_in[3];
    const float* beta  = (const float*)d_in[4];
    const float* lin_w = (const float*)d_in[5];
    const float* lin_b = (const float*)d_in[6];
    const float* tg1   = (const float*)d_in[7];
    const float* tg2   = (const float*)d_in[8];
    float* out = (float*)d_out;
    float* ws  = (float*)d_ws;   // 1 MB h + 16 KB meta

    capsA<<<NSITE/4, 256, 0, stream>>>(x, a, pose, tg1, lin_w, lin_b, out, ws);
    capsB<<<dim3(8, NSITE/4), 256, 0, stream>>>(a, pose, tg2, ws, alpha, beta, out);
}